// Round 14
// baseline (366.537 us; speedup 1.0000x reference)
//
#include <hip/hip_runtime.h>
#include <hip/hip_bf16.h>

#define N_ROWS 8192
#define DIM 512
#define SCALE 2.659f
#define MAXLOGIT 2.659f
#define LOG2E 1.4426950408889634f
#define NCHUNK 16
#define CHUNK 512
#define BM 128
#define BN 128
#define NCLS 128
#define GEMM_BLKS 1024        // 64 rowblks x 16 chunks
#define TOTAL_BLKS 3072       // 1024 gemm + 2048 class

typedef __attribute__((ext_vector_type(8))) short short8;
typedef __attribute__((ext_vector_type(4))) float f32x4;

// zero region: rs(8192) + cs(8192) + c_txt(65536) + c_img(65536) + cnt(128)
#define ZERO_F4 36896

__device__ __forceinline__ unsigned short f2bf(float f) {
    unsigned int u = __float_as_uint(f);
    u += 0x7fffu + ((u >> 16) & 1u);
    return (unsigned short)(u >> 16);
}

// ---------------------------------------------------------------- normalize
// One wave handles image row i AND text row i; also zeroes accumulators,
// the arrival counter, and out[0].
__global__ __launch_bounds__(256) void norm_cast_kernel(
    const float* __restrict__ text, const float* __restrict__ image,
    const int* __restrict__ labels,
    unsigned short* __restrict__ imgn, unsigned short* __restrict__ txtn,
    float4* __restrict__ zbase, float* __restrict__ sd,
    int* __restrict__ done, float* __restrict__ out)
{
    int zi = blockIdx.x * 256 + threadIdx.x;
    if (zi < ZERO_F4) zbase[zi] = make_float4(0.f, 0.f, 0.f, 0.f);
    if (zi == 0) { out[0] = 0.f; *done = 0; }

    int row  = blockIdx.x * 4 + (threadIdx.x >> 6);
    int lane = threadIdx.x & 63;
    const float4* si = (const float4*)(image + (size_t)row * DIM) + lane * 2;
    const float4* st = (const float4*)(text  + (size_t)row * DIM) + lane * 2;
    float4 a = si[0], b = si[1], c = st[0], d = st[1];
    float ssa = a.x*a.x + a.y*a.y + a.z*a.z + a.w*a.w
              + b.x*b.x + b.y*b.y + b.z*b.z + b.w*b.w;
    float sst = c.x*c.x + c.y*c.y + c.z*c.z + c.w*c.w
              + d.x*d.x + d.y*d.y + d.z*d.z + d.w*d.w;
    float sab = a.x*c.x + a.y*c.y + a.z*c.z + a.w*c.w
              + b.x*d.x + b.y*d.y + b.z*d.z + b.w*d.w;
    #pragma unroll
    for (int m = 1; m < 64; m <<= 1) {
        ssa += __shfl_xor(ssa, m, 64);
        sst += __shfl_xor(sst, m, 64);
        sab += __shfl_xor(sab, m, 64);
    }
    float sca = 1.0f / fmaxf(sqrtf(ssa), 1e-12f);
    float sct = 1.0f / fmaxf(sqrtf(sst), 1e-12f);
    uint4 oi, ot;
    oi.x = (unsigned)f2bf(a.x*sca) | ((unsigned)f2bf(a.y*sca) << 16);
    oi.y = (unsigned)f2bf(a.z*sca) | ((unsigned)f2bf(a.w*sca) << 16);
    oi.z = (unsigned)f2bf(b.x*sca) | ((unsigned)f2bf(b.y*sca) << 16);
    oi.w = (unsigned)f2bf(b.z*sca) | ((unsigned)f2bf(b.w*sca) << 16);
    ot.x = (unsigned)f2bf(c.x*sct) | ((unsigned)f2bf(c.y*sct) << 16);
    ot.y = (unsigned)f2bf(c.z*sct) | ((unsigned)f2bf(c.w*sct) << 16);
    ot.z = (unsigned)f2bf(d.x*sct) | ((unsigned)f2bf(d.y*sct) << 16);
    ot.w = (unsigned)f2bf(d.z*sct) | ((unsigned)f2bf(d.w*sct) << 16);
    *((uint4*)(imgn + (size_t)row * DIM) + lane) = oi;
    *((uint4*)(txtn + (size_t)row * DIM) + lane) = ot;
    if (lane == 0)
        sd[row] = (labels[row] < 0) ? sab * sca * sct : 0.0f;
}

// ---------------------------------------------------------------- mega
// Blocks [0, GEMM_BLKS): round-9-verified gemm core (4 LDS bufs, depth-2
//   prefetch, counted vmcnt(4), swizzled staging, conflicts=0).
// Blocks [GEMM_BLKS, TOTAL_BLKS): class-sum (8 slices x 128 cls x 2 mats).
// Every block arrives on a device-scope counter (release fence first);
// blocks 0..63 spin until all TOTAL_BLKS arrived, then run the loss tail.
#define ASYNC16(gp, lp) \
  __builtin_amdgcn_global_load_lds((const __attribute__((address_space(1))) void*)(gp), \
                                   (__attribute__((address_space(3))) void*)(lp), 16, 0, 0)

#define SFENCE __builtin_amdgcn_sched_barrier(0)

#define STAGE(b, tcol, k0)                                                    \
  {                                                                           \
    const unsigned short* Ap = A + (size_t)(rowBase + w*16 + srow) * DIM      \
                                 + (k0) + spsw;                               \
    const unsigned short* Bp = B + (size_t)((tcol) + w*16 + srow) * DIM       \
                                 + (k0) + spsw;                               \
    ASYNC16(Ap,            &Ald[b][(w*16) * 32]);                             \
    ASYNC16(Ap + 64 * DIM, &Ald[b][(64 + w*16) * 32]);                        \
    ASYNC16(Bp,            &Bld[b][(w*16) * 32]);                             \
    ASYNC16(Bp + 64 * DIM, &Bld[b][(64 + w*16) * 32]);                        \
  }

__global__ __launch_bounds__(256, 2) void mega_kernel(
    const unsigned short* __restrict__ imgn, const unsigned short* __restrict__ txtn,
    const int* __restrict__ labels,
    float* __restrict__ rs, float* __restrict__ cs,
    float* __restrict__ c_txt, float* __restrict__ c_img,
    int* __restrict__ cnt, const float* __restrict__ sd,
    int* __restrict__ done, float* __restrict__ out)
{
    __shared__ unsigned short Ald[4][BM * 32];
    __shared__ unsigned short Bld[4][BN * 32];
    __shared__ float red[2][BM];
    __shared__ float colb[2][CHUNK];
    __shared__ int   list[1024];
    __shared__ int   lcount;
    __shared__ float wsum[4];

    int tid  = threadIdx.x;
    int bid  = blockIdx.x;
    int lane = tid & 63;

    if (bid >= GEMM_BLKS) {
        // ---------------- class-sum path ----------------
        int blk = bid - GEMM_BLKS;
        int cls = blk & (NCLS - 1);
        int mat = (blk >> 7) & 1;              // 0: txt sums, 1: img sums
        int slc = blk >> 8;                    // 0..7
        const unsigned* src = (const unsigned*)(mat ? imgn : txtn);
        float* dst = mat ? c_img : c_txt;
        if (tid == 0) lcount = 0;
        __syncthreads();
        int base0 = slc * 1024;
        #pragma unroll
        for (int it = 0; it < 4; ++it) {
            int i  = base0 + it * 256 + tid;
            int lb = labels[i];
            if (lb == cls) { int s = atomicAdd(&lcount, 1); list[s & 1023] = i; }
        }
        __syncthreads();
        int m = lcount;
        if (m != 0) {
            if (mat == 0 && tid == 0) atomicAdd(&cnt[cls], m);
            float a0 = 0.f, a1 = 0.f;
            int r = 0;
            for (; r + 4 <= m; r += 4) {       // 4 independent loads in flight
                unsigned u0 = src[(size_t)list[r]   * (DIM/2) + tid];
                unsigned u1 = src[(size_t)list[r+1] * (DIM/2) + tid];
                unsigned u2 = src[(size_t)list[r+2] * (DIM/2) + tid];
                unsigned u3 = src[(size_t)list[r+3] * (DIM/2) + tid];
                a0 += __uint_as_float((u0 & 0xffffu) << 16) + __uint_as_float((u1 & 0xffffu) << 16)
                    + __uint_as_float((u2 & 0xffffu) << 16) + __uint_as_float((u3 & 0xffffu) << 16);
                a1 += __uint_as_float(u0 & 0xffff0000u) + __uint_as_float(u1 & 0xffff0000u)
                    + __uint_as_float(u2 & 0xffff0000u) + __uint_as_float(u3 & 0xffff0000u);
            }
            for (; r < m; ++r) {
                unsigned u = src[(size_t)list[r] * (DIM/2) + tid];
                a0 += __uint_as_float((u & 0xffffu) << 16);
                a1 += __uint_as_float(u & 0xffff0000u);
            }
            unsafeAtomicAdd(&dst[(size_t)cls * DIM + tid*2],     a0);
            unsafeAtomicAdd(&dst[(size_t)cls * DIM + tid*2 + 1], a1);
        }
    } else {
        // ---------------- GEMM path (round-9 core, verbatim) ----------------
        int rowblk = bid & 63;
        int chunk  = bid >> 6;    // consecutive bids share a chunk -> B L2-hot
        const unsigned short* A = imgn;
        const unsigned short* B = txtn;
        int rowBase  = rowblk * BM;
        int colBase0 = chunk * CHUNK;

        int w    = tid >> 6;
        int wr   = w >> 1, wc = w & 1;
        int q    = lane >> 4;
        int lm   = lane & 15;
        int qa   = q ^ ((lm >> 1) & 3);                     // swizzled read slot
        int srow = lane >> 2;
        int spsw = (((lane & 3) ^ ((lane >> 3) & 3)) * 8);  // swizzled src chunk

        float s_acc[16];
        #pragma unroll
        for (int i = 0; i < 16; ++i) s_acc[i] = 0.f;

        const float C1 = SCALE * LOG2E;
        const float C2 = -MAXLOGIT * LOG2E;

        STAGE(0, colBase0, 0);
        STAGE(1, colBase0, 32);
        SFENCE;
        asm volatile("s_waitcnt vmcnt(4)" ::: "memory");
        SFENCE;
        __builtin_amdgcn_s_barrier();
        SFENCE;

        #pragma unroll 1
        for (int tile = 0; tile < CHUNK / BN; ++tile) {
            f32x4 acc[4][4];
            #pragma unroll
            for (int mi = 0; mi < 4; ++mi)
              #pragma unroll
              for (int ni = 0; ni < 4; ++ni)
                acc[mi][ni] = (f32x4){0.f, 0.f, 0.f, 0.f};

            #pragma unroll
            for (int kt = 0; kt < DIM / 32; ++kt) {
                const int bcur = kt & 3;
                const int bpf  = (kt + 2) & 3;
                int g2 = tile * 16 + kt + 2;
                if (g2 < 64) {
                    int t2 = g2 >> 4, k2 = g2 & 15;
                    STAGE(bpf, colBase0 + t2 * BN, k2 * 32);
                }

                short8 af[4], bf[4];
                #pragma unroll
                for (int mi = 0; mi < 4; ++mi)
                    af[mi] = *(const short8*)(&Ald[bcur][(wr*64 + mi*16 + lm)*32 + qa*8]);
                #pragma unroll
                for (int ni = 0; ni < 4; ++ni)
                    bf[ni] = *(const short8*)(&Bld[bcur][(wc*64 + ni*16 + lm)*32 + qa*8]);
                #pragma unroll
                for (int mi = 0; mi < 4; ++mi)
                  #pragma unroll
                  for (int ni = 0; ni < 4; ++ni)
                    acc[mi][ni] = __builtin_amdgcn_mfma_f32_16x16x32_bf16(
                                      af[mi], bf[ni], acc[mi][ni], 0, 0, 0);

                if (kt == DIM / 32 - 1) {
                    #pragma unroll
                    for (int ni = 0; ni < 4; ++ni) {
                        float csum = 0.f;
                        #pragma unroll
                        for (int mi = 0; mi < 4; ++mi) {
                          #pragma unroll
                          for (int r = 0; r < 4; ++r) {
                            float e = __builtin_amdgcn_exp2f(fmaf(acc[mi][ni][r], C1, C2));
                            s_acc[mi*4 + r] += e;
                            csum += e;
                          }
                        }
                        csum += __shfl_xor(csum, 16, 64);
                        csum += __shfl_xor(csum, 32, 64);
                        if (q == 0)
                            colb[wr][tile*BN + wc*64 + ni*16 + lm] = csum;
                    }
                }

                SFENCE;
                if (g2 < 64) asm volatile("s_waitcnt vmcnt(4)" ::: "memory");
                else         asm volatile("s_waitcnt vmcnt(0)" ::: "memory");
                SFENCE;
                __builtin_amdgcn_s_barrier();
                SFENCE;
            }
        }

        #pragma unroll
        for (int idx = 0; idx < 16; ++idx) {
            float s = s_acc[idx];
            #pragma unroll
            for (int m = 1; m < 16; m <<= 1) s += __shfl_xor(s, m, 64);
            s_acc[idx] = s;
        }
        if (lm == 0) {
            #pragma unroll
            for (int idx = 0; idx < 16; ++idx) {
                int rl = wr*64 + (idx>>2)*16 + q*4 + (idx&3);
                red[wc][rl] = s_acc[idx];
            }
        }
        __syncthreads();
        if (tid < BM)
            unsafeAtomicAdd(&rs[rowBase + tid], red[0][tid] + red[1][tid]);
        for (int c = tid; c < CHUNK; c += 256)
            unsafeAtomicAdd(&cs[colBase0 + c], colb[0][c] + colb[1][c]);
    }

    // ---------------- arrive (all blocks) ----------------
    // __syncthreads drains every wave's outstanding vmem (incl. atomics)
    // before the release fence; threadfence = agent release (L2 writeback).
    __syncthreads();
    if (tid == 0) {
        __threadfence();
        atomicAdd(done, 1);
    }

    // ---------------- loss tail (blocks 0..63, gated on all arrivals) ------
    // loss*2N = Sum_i (M+log rs_i) + Sum_i (M+log cs_i)
    //   - 2*scale*[ Sum_l <c_img[l],c_txt[l]>/cnt_l + Sum_{lab=-1} <a_i,b_i> ]
    if (bid < 64) {
        if (tid == 0) {
            while (__hip_atomic_load(done, __ATOMIC_ACQUIRE,
                                     __HIP_MEMORY_SCOPE_AGENT) < TOTAL_BLKS)
                __builtin_amdgcn_s_sleep(8);
            __threadfence();               // acquire: invalidate L1/L2
        }
        __syncthreads();

        int w = tid >> 6;
        int gidx = bid * 256 + tid;        // 0..16383
        float local;
        if (gidx < N_ROWS)
            local = (MAXLOGIT + logf(rs[gidx])) - 2.0f * SCALE * sd[gidx];
        else
            local = MAXLOGIT + logf(cs[gidx - N_ROWS]);

        int cls = bid * 2 + (tid >> 7);    // 0..127
        int e0  = (tid & 127) * 4;
        int n   = cnt[cls];
        if (n > 0) {
            float4 x = *(const float4*)(c_txt + (size_t)cls * DIM + e0);
            float4 y = *(const float4*)(c_img + (size_t)cls * DIM + e0);
            float dotp = x.x*y.x + x.y*y.y + x.z*y.z + x.w*y.w;
            local -= 2.0f * SCALE * dotp / (float)n;
        }

        #pragma unroll
        for (int m = 1; m < 64; m <<= 1) local += __shfl_xor(local, m, 64);
        if (lane == 0) wsum[w] = local;
        __syncthreads();
        if (tid == 0)
            unsafeAtomicAdd(out, (wsum[0] + wsum[1] + wsum[2] + wsum[3])
                                 * (1.0f / (2 * N_ROWS)));
    }
}

// ---------------------------------------------------------------- launch
extern "C" void kernel_launch(void* const* d_in, const int* in_sizes, int n_in,
                              void* d_out, int out_size, void* d_ws, size_t ws_size,
                              hipStream_t stream)
{
    const float* text   = (const float*)d_in[0];
    const float* image  = (const float*)d_in[1];
    const int*   labels = (const int*)d_in[2];

    unsigned short* imgn = (unsigned short*)d_ws;
    unsigned short* txtn = imgn + (size_t)N_ROWS * DIM;
    char* p = (char*)d_ws + 2 * (size_t)N_ROWS * DIM * sizeof(unsigned short);
    float* rs    = (float*)p;                       // 8192 f32  (zeroed)
    float* cs    = rs + N_ROWS;                     // 8192 f32  (zeroed)
    float* c_txt = cs + N_ROWS;                     // 128*512 f32 (zeroed)
    float* c_img = c_txt + (size_t)NCLS * DIM;      // 128*512 f32 (zeroed)
    int*   cnt   = (int*)(c_img + (size_t)NCLS * DIM); // 128 (zeroed)
    float* sd    = (float*)(cnt + NCLS);            // 8192 f32 (fully written)
    int*   done  = (int*)(sd + N_ROWS);             // arrival counter (zeroed)
    float* out = (float*)d_out;

    hipLaunchKernelGGL(norm_cast_kernel, dim3(N_ROWS / 4), dim3(256), 0, stream,
                       text, image, labels, imgn, txtn, (float4*)rs, sd, done, out);
    hipLaunchKernelGGL(mega_kernel, dim3(TOTAL_BLKS), dim3(256), 0, stream,
                       imgn, txtn, labels, rs, cs, c_txt, c_img, cnt, sd, done, out);
}

// Round 15
// 167.893 us; speedup vs baseline: 2.1832x; 2.1832x over previous
//
#include <hip/hip_runtime.h>
#include <hip/hip_bf16.h>

#define N_ROWS 8192
#define DIM 512
#define SCALE 2.659f
#define MAXLOGIT 2.659f
#define LOG2E 1.4426950408889634f
#define NCHUNK 16
#define CHUNK 512
#define BM 128
#define BN 128
#define NCLS 128
#define GEMM_BLKS 1024   // 64 rowblks x 16 chunks

typedef __attribute__((ext_vector_type(8))) short short8;
typedef __attribute__((ext_vector_type(4))) float f32x4;

// zero region: rs(8192) + cs(8192) + c_txt(65536) + c_img(65536) + cnt(128)
#define ZERO_F4 36896

__device__ __forceinline__ unsigned short f2bf(float f) {
    unsigned int u = __float_as_uint(f);
    u += 0x7fffu + ((u >> 16) & 1u);
    return (unsigned short)(u >> 16);
}

// ---------------------------------------------------------------- normalize
// One wave handles image row i AND text row i: computes both norms, writes
// both bf16 rows, and emits the self-dot <a_i,b_i> (needed when label==-1).
// Also zero-initializes rs/cs/c_txt/c_img/cnt accumulators and out[0].
__global__ __launch_bounds__(256) void norm_cast_kernel(
    const float* __restrict__ text, const float* __restrict__ image,
    const int* __restrict__ labels,
    unsigned short* __restrict__ imgn, unsigned short* __restrict__ txtn,
    float4* __restrict__ zbase, float* __restrict__ sd, float* __restrict__ out)
{
    int zi = blockIdx.x * 256 + threadIdx.x;
    if (zi < ZERO_F4) zbase[zi] = make_float4(0.f, 0.f, 0.f, 0.f);
    if (zi == 0) out[0] = 0.f;

    int row  = blockIdx.x * 4 + (threadIdx.x >> 6);
    int lane = threadIdx.x & 63;
    const float4* si = (const float4*)(image + (size_t)row * DIM) + lane * 2;
    const float4* st = (const float4*)(text  + (size_t)row * DIM) + lane * 2;
    float4 a = si[0], b = si[1], c = st[0], d = st[1];
    float ssa = a.x*a.x + a.y*a.y + a.z*a.z + a.w*a.w
              + b.x*b.x + b.y*b.y + b.z*b.z + b.w*b.w;
    float sst = c.x*c.x + c.y*c.y + c.z*c.z + c.w*c.w
              + d.x*d.x + d.y*d.y + d.z*d.z + d.w*d.w;
    float sab = a.x*c.x + a.y*c.y + a.z*c.z + a.w*c.w
              + b.x*d.x + b.y*d.y + b.z*d.z + b.w*d.w;
    #pragma unroll
    for (int m = 1; m < 64; m <<= 1) {
        ssa += __shfl_xor(ssa, m, 64);
        sst += __shfl_xor(sst, m, 64);
        sab += __shfl_xor(sab, m, 64);
    }
    float sca = 1.0f / fmaxf(sqrtf(ssa), 1e-12f);
    float sct = 1.0f / fmaxf(sqrtf(sst), 1e-12f);
    uint4 oi, ot;
    oi.x = (unsigned)f2bf(a.x*sca) | ((unsigned)f2bf(a.y*sca) << 16);
    oi.y = (unsigned)f2bf(a.z*sca) | ((unsigned)f2bf(a.w*sca) << 16);
    oi.z = (unsigned)f2bf(b.x*sca) | ((unsigned)f2bf(b.y*sca) << 16);
    oi.w = (unsigned)f2bf(b.z*sca) | ((unsigned)f2bf(b.w*sca) << 16);
    ot.x = (unsigned)f2bf(c.x*sct) | ((unsigned)f2bf(c.y*sct) << 16);
    ot.y = (unsigned)f2bf(c.z*sct) | ((unsigned)f2bf(c.w*sct) << 16);
    ot.z = (unsigned)f2bf(d.x*sct) | ((unsigned)f2bf(d.y*sct) << 16);
    ot.w = (unsigned)f2bf(d.z*sct) | ((unsigned)f2bf(d.w*sct) << 16);
    *((uint4*)(imgn + (size_t)row * DIM) + lane) = oi;
    *((uint4*)(txtn + (size_t)row * DIM) + lane) = ot;
    if (lane == 0)
        sd[row] = (labels[row] < 0) ? sab * sca * sct : 0.0f;
}

// ---------------------------------------------------------------- fused GEMM
// Blocks [0, GEMM_BLKS): 128x128 tiles over a 512-col chunk (round-7 proven
//   schedule: 4 LDS buffers, depth-2 prefetch, counted vmcnt(4), 2 blk/CU).
// Blocks [GEMM_BLKS, +2048): class-sum path (8 slices x 128 cls x 2 mats).
// LDS bank-conflict swizzle (both-sides XOR involution, rule #21):
//   stage SOURCE k-chunk = (l&3) ^ ((l>>3)&3)  (LDS dest stays linear),
//   read slot            = q ^ ((lm>>1)&3).
//   Each 8-lane issue group then covers all 8 bank positions (2 parities x
//   4 slots) -> ds_read_b128 at the structural floor (measured: conflicts=0).
#define ASYNC16(gp, lp) \
  __builtin_amdgcn_global_load_lds((const __attribute__((address_space(1))) void*)(gp), \
                                   (__attribute__((address_space(3))) void*)(lp), 16, 0, 0)

#define SFENCE __builtin_amdgcn_sched_barrier(0)

#define STAGE(b, tcol, k0)                                                    \
  {                                                                           \
    const unsigned short* Ap = A + (size_t)(rowBase + w*16 + srow) * DIM      \
                                 + (k0) + spsw;                               \
    const unsigned short* Bp = B + (size_t)((tcol) + w*16 + srow) * DIM       \
                                 + (k0) + spsw;                               \
    ASYNC16(Ap,            &Ald[b][(w*16) * 32]);                             \
    ASYNC16(Ap + 64 * DIM, &Ald[b][(64 + w*16) * 32]);                        \
    ASYNC16(Bp,            &Bld[b][(w*16) * 32]);                             \
    ASYNC16(Bp + 64 * DIM, &Bld[b][(64 + w*16) * 32]);                        \
  }

__global__ __launch_bounds__(256, 2) void gemm_fused_kernel(
    const unsigned short* __restrict__ imgn, const unsigned short* __restrict__ txtn,
    const int* __restrict__ labels,
    float* __restrict__ rs, float* __restrict__ cs,
    float* __restrict__ c_txt, float* __restrict__ c_img, int* __restrict__ cnt)
{
    __shared__ unsigned short Ald[4][BM * 32];
    __shared__ unsigned short Bld[4][BN * 32];
    __shared__ float red[2][BM];
    __shared__ float colb[2][CHUNK];
    __shared__ int   list[1024];
    __shared__ int   lcount;

    int tid  = threadIdx.x;

    // ---------------- class-sum path ----------------
    if (blockIdx.x >= GEMM_BLKS) {
        int blk = blockIdx.x - GEMM_BLKS;
        int cls = blk & (NCLS - 1);
        int mat = (blk >> 7) & 1;              // 0: txt sums, 1: img sums
        int slc = blk >> 8;                    // 0..7
        const unsigned* src = (const unsigned*)(mat ? imgn : txtn);
        float* dst = mat ? c_img : c_txt;
        if (tid == 0) lcount = 0;
        __syncthreads();
        int base0 = slc * 1024;
        #pragma unroll
        for (int it = 0; it < 4; ++it) {
            int i  = base0 + it * 256 + tid;
            int lb = labels[i];
            if (lb == cls) { int s = atomicAdd(&lcount, 1); list[s & 1023] = i; }
        }
        __syncthreads();
        int m = lcount;
        if (m == 0) return;
        if (mat == 0 && tid == 0) atomicAdd(&cnt[cls], m);
        float a0 = 0.f, a1 = 0.f;
        int r = 0;
        for (; r + 4 <= m; r += 4) {           // 4 independent loads in flight
            unsigned u0 = src[(size_t)list[r]   * (DIM/2) + tid];
            unsigned u1 = src[(size_t)list[r+1] * (DIM/2) + tid];
            unsigned u2 = src[(size_t)list[r+2] * (DIM/2) + tid];
            unsigned u3 = src[(size_t)list[r+3] * (DIM/2) + tid];
            a0 += __uint_as_float((u0 & 0xffffu) << 16) + __uint_as_float((u1 & 0xffffu) << 16)
                + __uint_as_float((u2 & 0xffffu) << 16) + __uint_as_float((u3 & 0xffffu) << 16);
            a1 += __uint_as_float(u0 & 0xffff0000u) + __uint_as_float(u1 & 0xffff0000u)
                + __uint_as_float(u2 & 0xffff0000u) + __uint_as_float(u3 & 0xffff0000u);
        }
        for (; r < m; ++r) {
            unsigned u = src[(size_t)list[r] * (DIM/2) + tid];
            a0 += __uint_as_float((u & 0xffffu) << 16);
            a1 += __uint_as_float(u & 0xffff0000u);
        }
        unsafeAtomicAdd(&dst[(size_t)cls * DIM + tid*2],     a0);
        unsafeAtomicAdd(&dst[(size_t)cls * DIM + tid*2 + 1], a1);
        return;
    }

    // ---------------- GEMM path ----------------
    int bid    = blockIdx.x;
    int rowblk = bid & 63;
    int chunk  = bid >> 6;        // consecutive bids share a chunk -> B L2-hot
    const unsigned short* A = imgn;
    const unsigned short* B = txtn;
    int rowBase  = rowblk * BM;
    int colBase0 = chunk * CHUNK;

    int lane = tid & 63;
    int w    = tid >> 6;
    int wr   = w >> 1, wc = w & 1;
    int q    = lane >> 4;
    int lm   = lane & 15;
    int qa   = q ^ ((lm >> 1) & 3);   // swizzled read slot

    float s_acc[16];
    #pragma unroll
    for (int i = 0; i < 16; ++i) s_acc[i] = 0.f;

    int srow = lane >> 2;                               // staging row in group
    int spsw = (((lane & 3) ^ ((lane >> 3) & 3)) * 8);  // swizzled src k-chunk

    const float C1 = SCALE * LOG2E;
    const float C2 = -MAXLOGIT * LOG2E;

    // prologue: stage step 0 -> buf0, step 1 -> buf1; wait only for step 0.
    STAGE(0, colBase0, 0);
    STAGE(1, colBase0, 32);
    SFENCE;
    asm volatile("s_waitcnt vmcnt(4)" ::: "memory");
    SFENCE;
    __builtin_amdgcn_s_barrier();
    SFENCE;

    #pragma unroll 1
    for (int tile = 0; tile < CHUNK / BN; ++tile) {
        f32x4 acc[4][4];
        #pragma unroll
        for (int mi = 0; mi < 4; ++mi)
          #pragma unroll
          for (int ni = 0; ni < 4; ++ni)
            acc[mi][ni] = (f32x4){0.f, 0.f, 0.f, 0.f};

        #pragma unroll
        for (int kt = 0; kt < DIM / 32; ++kt) {
            // step g = tile*16 + kt; tile*16 % 4 == 0 -> static buffer idx.
            const int bcur = kt & 3;
            const int bpf  = (kt + 2) & 3;
            int g2 = tile * 16 + kt + 2;
            if (g2 < 64) {
                int t2 = g2 >> 4, k2 = g2 & 15;
                STAGE(bpf, colBase0 + t2 * BN, k2 * 32);
            }

            short8 af[4], bf[4];
            #pragma unroll
            for (int mi = 0; mi < 4; ++mi)
                af[mi] = *(const short8*)(&Ald[bcur][(wr*64 + mi*16 + lm)*32 + qa*8]);
            #pragma unroll
            for (int ni = 0; ni < 4; ++ni)
                bf[ni] = *(const short8*)(&Bld[bcur][(wc*64 + ni*16 + lm)*32 + qa*8]);
            #pragma unroll
            for (int mi = 0; mi < 4; ++mi)
              #pragma unroll
              for (int ni = 0; ni < 4; ++ni)
                acc[mi][ni] = __builtin_amdgcn_mfma_f32_16x16x32_bf16(
                                  af[mi], bf[ni], acc[mi][ni], 0, 0, 0);

            // tile epilogue before the step wait: extra cover for prefetch.
            if (kt == DIM / 32 - 1) {
                #pragma unroll
                for (int ni = 0; ni < 4; ++ni) {
                    float csum = 0.f;
                    #pragma unroll
                    for (int mi = 0; mi < 4; ++mi) {
                      #pragma unroll
                      for (int r = 0; r < 4; ++r) {
                        float e = __builtin_amdgcn_exp2f(fmaf(acc[mi][ni][r], C1, C2));
                        s_acc[mi*4 + r] += e;
                        csum += e;
                      }
                    }
                    csum += __shfl_xor(csum, 16, 64);
                    csum += __shfl_xor(csum, 32, 64);
                    if (q == 0)
                        colb[wr][tile*BN + wc*64 + ni*16 + lm] = csum;
                }
            }

            // counted wait: <=4 outstanding => stage(g+1) landed; barrier =>
            // all waves' stage(g+1) landed before step g+1. Tail drains.
            SFENCE;
            if (g2 < 64) asm volatile("s_waitcnt vmcnt(4)" ::: "memory");
            else         asm volatile("s_waitcnt vmcnt(0)" ::: "memory");
            SFENCE;
            __builtin_amdgcn_s_barrier();
            SFENCE;
        }
    }

    // row stats: reduce across the 16 column-lanes (low 4 lane bits)
    #pragma unroll
    for (int idx = 0; idx < 16; ++idx) {
        float s = s_acc[idx];
        #pragma unroll
        for (int m = 1; m < 16; m <<= 1) s += __shfl_xor(s, m, 64);
        s_acc[idx] = s;
    }
    if (lm == 0) {
        #pragma unroll
        for (int idx = 0; idx < 16; ++idx) {
            int rl = wr*64 + (idx>>2)*16 + q*4 + (idx&3);
            red[wc][rl] = s_acc[idx];
        }
    }
    __syncthreads();
    if (tid < BM)
        unsafeAtomicAdd(&rs[rowBase + tid], red[0][tid] + red[1][tid]);
    for (int c = tid; c < CHUNK; c += 256)
        unsafeAtomicAdd(&cs[colBase0 + c], colb[0][c] + colb[1][c]);
}

// ---------------------------------------------------------------- final loss
// loss*2N = Sum_i (M + log rs_i) + Sum_i (M + log cs_i)
//           - 2*scale*[ Sum_l <c_img[l],c_txt[l]>/cnt_l + Sum_{lab=-1} <a_i,b_i> ]
__global__ __launch_bounds__(256) void loss_tail_kernel(
    const float* __restrict__ rs, const float* __restrict__ cs,
    const float* __restrict__ sd, const float* __restrict__ c_txt,
    const float* __restrict__ c_img, const int* __restrict__ cnt,
    float* __restrict__ out)
{
    __shared__ float wsum[4];
    int tid = threadIdx.x, lane = tid & 63, w = tid >> 6;
    int gidx = blockIdx.x * 256 + tid;           // 0..16383
    float local;
    if (gidx < N_ROWS)
        local = (MAXLOGIT + logf(rs[gidx])) - 2.0f * SCALE * sd[gidx];
    else
        local = MAXLOGIT + logf(cs[gidx - N_ROWS]);

    // class-dot portion: 2 classes per block, 4 dims per thread
    int cls = blockIdx.x * 2 + (tid >> 7);       // 0..127
    int e0  = (tid & 127) * 4;
    int n   = cnt[cls];
    if (n > 0) {
        float4 x = *(const float4*)(c_txt + (size_t)cls * DIM + e0);
        float4 y = *(const float4*)(c_img + (size_t)cls * DIM + e0);
        float dotp = x.x*y.x + x.y*y.y + x.z*y.z + x.w*y.w;
        local -= 2.0f * SCALE * dotp / (float)n;
    }

    #pragma unroll
    for (int m = 1; m < 64; m <<= 1) local += __shfl_xor(local, m, 64);
    if (lane == 0) wsum[w] = local;
    __syncthreads();
    if (tid == 0)
        unsafeAtomicAdd(out, (wsum[0] + wsum[1] + wsum[2] + wsum[3])
                             * (1.0f / (2 * N_ROWS)));
}

// ---------------------------------------------------------------- launch
extern "C" void kernel_launch(void* const* d_in, const int* in_sizes, int n_in,
                              void* d_out, int out_size, void* d_ws, size_t ws_size,
                              hipStream_t stream)
{
    const float* text   = (const float*)d_in[0];
    const float* image  = (const float*)d_in[1];
    const int*   labels = (const int*)d_in[2];

    unsigned short* imgn = (unsigned short*)d_ws;
    unsigned short* txtn = imgn + (size_t)N_ROWS * DIM;
    char* p = (char*)d_ws + 2 * (size_t)N_ROWS * DIM * sizeof(unsigned short);
    float* rs    = (float*)p;                       // 8192 f32  (zeroed)
    float* cs    = rs + N_ROWS;                     // 8192 f32  (zeroed)
    float* c_txt = cs + N_ROWS;                     // 128*512 f32 (zeroed)
    float* c_img = c_txt + (size_t)NCLS * DIM;      // 128*512 f32 (zeroed)
    int*   cnt   = (int*)(c_img + (size_t)NCLS * DIM); // 128 (zeroed)
    float* sd    = (float*)(cnt + NCLS);            // 8192 f32 (fully written)
    float* out = (float*)d_out;

    hipLaunchKernelGGL(norm_cast_kernel, dim3(N_ROWS / 4), dim3(256), 0, stream,
                       text, image, labels, imgn, txtn, (float4*)rs, sd, out);
    hipLaunchKernelGGL(gemm_fused_kernel, dim3(GEMM_BLKS + 2048), dim3(256), 0, stream,
                       imgn, txtn, labels, rs, cs, c_txt, c_img, cnt);
    hipLaunchKernelGGL(loss_tail_kernel, dim3(64), dim3(256), 0, stream,
                       rs, cs, sd, c_txt, c_img, cnt, out);
}